// Round 14
// baseline (171.049 us; speedup 1.0000x reference)
//
#include <hip/hip_runtime.h>

// MegaNeRF fused MoE-MLP for MI355X (gfx950) — round 14.
// = round 10 expert_mlp (best, ~85us) + two-tiles-per-block with T14 async
// stage (tile B's gather issued after epi1(A), written to sFb during G3(A);
// hides gather under G2, tile B's weight loads hit warm L1/L2). pk2 restored
// (r13: inline-asm cvt_pk hurt scheduling, per m240). Fused prep kept.

typedef __attribute__((ext_vector_type(8))) short   s16x8;
typedef __attribute__((ext_vector_type(4))) float   f32x4;

#define NPTS  65536
#define E_    8
#define DIN   90
#define H_    256
#define DOUT  4

// packed weight layout: [e][ct][ks][lane][j] bf16, 512 elems per (e,ct,ks)
#define W1P_ELEMS (E_*16*3*512)   // 196608
#define W2P_ELEMS (E_*16*8*512)   // 524288
#define W3P_ELEMS (E_*1*8*512)    // 32768
#define W2P_OFF   (W1P_ELEMS)
#define W3P_OFF   (W1P_ELEMS + W2P_ELEMS)
#define WSP_TOTAL (W1P_ELEMS + W2P_ELEMS + W3P_ELEMS)   // 753664
#define WSP_BYTES (WSP_TOTAL*2)
#define CNT_OFF   WSP_BYTES                  // int[8]
#define LIST_OFF  (WSP_BYTES + 32)           // u16[E_*NPTS] = 1 MB
#define XB_OFF    (LIST_OFF + E_*NPTS*2)     // u16[NPTS*96] = 12.6 MB
#define WL_OFF    (XB_OFF + (size_t)NPTS*96*2)  // f32[E_*NPTS] = 2 MB

// fused-prep block ranges (256 threads each)
#define PREP_BLKS (WSP_TOTAL/256)            // 2944 (exact)
#define XPK_BLKS  (NPTS*48/256)              // 12288 (exact)
#define RC_BLKS   (NPTS/256)                 // 256

__device__ __forceinline__ unsigned short f2bf(float f) {
  union { float f; unsigned u; } v; v.f = f;
  unsigned u = v.u;
  u += 0x7fffu + ((u >> 16) & 1u);   // round-to-nearest-even
  return (unsigned short)(u >> 16);
}
__device__ __forceinline__ unsigned pk2(float a, float b) {
  return (unsigned)f2bf(a) | ((unsigned)f2bf(b) << 16);
}

// ---------------- fused prep: weights-pack | x-pack+out-zero | route --------
__global__ __launch_bounds__(256)
void fused_prep(const float* __restrict__ x,
                const float* __restrict__ cen,
                const float* __restrict__ W1,
                const float* __restrict__ W2,
                const float* __restrict__ W3,
                unsigned short* __restrict__ P,
                unsigned* __restrict__ xb32,
                float* __restrict__ out,
                int* __restrict__ counts,
                unsigned short* __restrict__ lists,
                float* __restrict__ wlist) {
  const int b   = blockIdx.x;
  const int tid = threadIdx.x;

  if (b < PREP_BLKS) {
    int idx = b*256 + tid;
    float val;
    if (idx < W2P_OFF) {                       // W1: (e,90,256), K padded 96
      int f = idx;
      int j = f & 7, l = (f >> 3) & 63, t = f >> 9;
      int ks = t % 3; t /= 3;
      int ct = t & 15, e = t >> 4;
      int k = ks*32 + (l>>4)*8 + j;
      int n = ct*16 + (l & 15);
      val = (k < DIN) ? W1[((size_t)e*DIN + k)*H_ + n] : 0.f;
    } else if (idx < W3P_OFF) {                // W2: (e,256,256)
      int f = idx - W2P_OFF;
      int j = f & 7, l = (f >> 3) & 63, t = f >> 9;
      int ks = t & 7; t >>= 3;
      int ct = t & 15, e = t >> 4;
      int k = ks*32 + (l>>4)*8 + j;
      int n = ct*16 + (l & 15);
      val = W2[((size_t)e*H_ + k)*H_ + n];
    } else {                                   // W3: (e,256,4), N padded to 16
      int f = idx - W3P_OFF;
      int j = f & 7, l = (f >> 3) & 63, t = f >> 9;
      int ks = t & 7, e = t >> 3;
      int k = ks*32 + (l>>4)*8 + j;
      int n = l & 15;
      val = (n < DOUT) ? W3[((size_t)e*H_ + k)*DOUT + n] : 0.f;
    }
    P[idx] = f2bf(val);

  } else if (b < PREP_BLKS + XPK_BLKS) {
    int i = (b - PREP_BLKS)*256 + tid;
    if (i < NPTS*DOUT) out[i] = 0.f;
    int n = i / 48, c = i - n*48;
    const float* xr = x + (size_t)n*93 + 3;
    float v0 = (2*c   < DIN) ? xr[2*c]   : 0.f;
    float v1 = (2*c+1 < DIN) ? xr[2*c+1] : 0.f;
    xb32[(size_t)n*48 + c] = pk2(v0, v1);

  } else {
    int gid = (b - PREP_BLKS - XPK_BLKS)*256 + tid;
    __shared__ int lcnt[E_], lbase[E_];
    if (tid < E_) lcnt[tid] = 0;
    __syncthreads();

    const float* xr = x + (size_t)gid*93;
    float px = xr[0], py = xr[1], pz = xr[2];
    float d[E_], dmin = 1e30f;
    #pragma unroll
    for (int e = 0; e < E_; e++) {
      float dx = px - cen[e*3+0], dy = py - cen[e*3+1], dz = pz - cen[e*3+2];
      d[e] = sqrtf(dx*dx + dy*dy + dz*dz);
      dmin = fminf(dmin, d[e]);
    }
    float inv[E_], s = 0.f;
    int act = 0;
    #pragma unroll
    for (int e = 0; e < E_; e++) {
      float iv = (d[e] > 2.0f*dmin) ? 0.f : 1.0f/(d[e] + 1e-8f);  // ref predicate
      inv[e] = iv; s += iv;
      if (iv > 0.f) act |= (1 << e);
    }
    float rs = 1.0f/s;
    int myoff[E_];
    #pragma unroll
    for (int e = 0; e < E_; e++)
      if ((act >> e) & 1) myoff[e] = atomicAdd(&lcnt[e], 1);
    __syncthreads();
    if (tid < E_) lbase[tid] = atomicAdd(&counts[tid], lcnt[tid]);
    __syncthreads();
    #pragma unroll
    for (int e = 0; e < E_; e++)
      if ((act >> e) & 1) {
        int slot = e*NPTS + lbase[e] + myoff[e];
        lists[slot] = (unsigned short)gid;
        wlist[slot] = inv[e]*rs;
      }
  }
}

// ---------------- per-expert transposed MLP, 2x64 points per block ----------
__global__ __launch_bounds__(256, 3)
void expert_mlp(const float* __restrict__ b1,
                const float* __restrict__ b2,
                const float* __restrict__ b3,
                const unsigned short* __restrict__ P,
                const unsigned short* __restrict__ XB,
                const int* __restrict__ counts,
                const unsigned short* __restrict__ lists,
                const float* __restrict__ wlist,
                float* __restrict__ out) {
  const int e   = blockIdx.y;
  const int cnt = counts[e];
  const int tp  = blockIdx.x;          // tile-pair; tiles 2tp, 2tp+1
  if (tp*128 >= cnt) return;

  __shared__ __attribute__((aligned(16))) unsigned short sFb[64*128]; // 16KB
  __shared__ __attribute__((aligned(16))) unsigned short sH[64*256];  // 32KB

  const int tid  = threadIdx.x;
  const int wid  = tid >> 6;
  const int lane = tid & 63;
  const int lg   = lane >> 4;
  const int lr   = lane & 15;
  const int row  = tid >> 2;           // staging: 4 threads per row

  // ---- stage tile A (2tp) into sFb
  {
    int slot = tp*128 + row;
    int p    = (slot < cnt) ? (int)lists[e*NPTS + slot] : 0;
    const unsigned short* src = XB + (size_t)p*96;
    #pragma unroll
    for (int it = 0; it < 3; it++) {
      int chk = (tid & 3) + 4*it;
      s16x8 v = *(const s16x8*)(src + chk*8);
      int byt = (chk*16) ^ ((row & 7) << 4);
      *(s16x8*)((char*)sFb + row*256 + byt) = v;
    }
  }
  __syncthreads();

  const bool have2 = (tp*128 + 64) < cnt;
  s16x8 stg0, stg1, stg2;

  const unsigned short* PW1 = P + (((e*16 + wid*4)*3) << 9) + lane*8;
  const unsigned short* PW2 = P + W2P_OFF + (((e*16 + wid*4)*8) << 9) + lane*8;

  #pragma unroll
  for (int sub = 0; sub < 2; ++sub) {
    if (sub == 1 && !have2) break;     // block-uniform
    const int t = 2*tp + sub;

    f32x4 acc[4][4];   // [nt][bt]
    // ========== G1^T: K=96, B-frags from sFb ==========
    #pragma unroll
    for (int nt = 0; nt < 4; nt++)
      #pragma unroll
      for (int bt = 0; bt < 4; bt++) acc[nt][bt] = (f32x4){0.f,0.f,0.f,0.f};
    #pragma unroll
    for (int ks = 0; ks < 3; ks++) {
      s16x8 bfr[4];
      #pragma unroll
      for (int bt = 0; bt < 4; bt++) {
        int m = 16*bt + lr;
        int byt = (64*ks + 16*lg) ^ ((m & 7) << 4);
        bfr[bt] = *(const s16x8*)((const char*)sFb + m*256 + byt);
      }
      #pragma unroll
      for (int nt = 0; nt < 4; nt++) {
        s16x8 a = *(const s16x8*)(PW1 + ((nt*3 + ks) << 9));
        #pragma unroll
        for (int bt = 0; bt < 4; bt++)
          acc[nt][bt] = __builtin_amdgcn_mfma_f32_16x16x32_bf16(a, bfr[bt], acc[nt][bt], 0,0,0);
      }
    }
    // epilogue 1: bias+relu, pack, 8B write to sH (XOR swz)
    #pragma unroll
    for (int nt = 0; nt < 4; nt++) {
      int ct = wid*4 + nt;
      float4 bv = *(const float4*)&b1[e*H_ + ct*16 + lg*4];
      #pragma unroll
      for (int bt = 0; bt < 4; bt++) {
        float v0 = fmaxf(acc[nt][bt][0] + bv.x, 0.f);
        float v1 = fmaxf(acc[nt][bt][1] + bv.y, 0.f);
        float v2 = fmaxf(acc[nt][bt][2] + bv.z, 0.f);
        float v3 = fmaxf(acc[nt][bt][3] + bv.w, 0.f);
        int m   = 16*bt + lr;
        int byt = (32*ct + 8*lg) ^ ((m & 7) << 4);
        uint2 pkd; pkd.x = pk2(v0, v1); pkd.y = pk2(v2, v3);
        *(uint2*)((char*)sH + m*512 + byt) = pkd;
      }
    }
    __syncthreads();   // A: epi1 done -> G2 may read sH; sFb readers done too

    // ---- T14 issue: tile B's gather into registers (hidden under G2)
    if (sub == 0 && have2) {
      int slot = tp*128 + 64 + row;
      int p    = (slot < cnt) ? (int)lists[e*NPTS + slot] : 0;
      const unsigned short* src = XB + (size_t)p*96;
      stg0 = *(const s16x8*)(src + ((tid & 3) + 0)*8);
      stg1 = *(const s16x8*)(src + ((tid & 3) + 4)*8);
      stg2 = *(const s16x8*)(src + ((tid & 3) + 8)*8);
    }

    // ========== G2^T: K=256 ==========
    #pragma unroll
    for (int nt = 0; nt < 4; nt++)
      #pragma unroll
      for (int bt = 0; bt < 4; bt++) acc[nt][bt] = (f32x4){0.f,0.f,0.f,0.f};
    #pragma unroll
    for (int ks = 0; ks < 8; ks++) {
      s16x8 bfr[4];
      #pragma unroll
      for (int bt = 0; bt < 4; bt++) {
        int m = 16*bt + lr;
        int byt = (64*ks + 16*lg) ^ ((m & 7) << 4);
        bfr[bt] = *(const s16x8*)((const char*)sH + m*512 + byt);
      }
      #pragma unroll
      for (int nt = 0; nt < 4; nt++) {
        s16x8 a = *(const s16x8*)(PW2 + ((nt*8 + ks) << 9));
        #pragma unroll
        for (int bt = 0; bt < 4; bt++)
          acc[nt][bt] = __builtin_amdgcn_mfma_f32_16x16x32_bf16(a, bfr[bt], acc[nt][bt], 0,0,0);
      }
    }
    __syncthreads();   // B: G2 reads of h1 done -> epi2 may overwrite sH

    // epilogue 2: bias+relu -> sH (h2)
    #pragma unroll
    for (int nt = 0; nt < 4; nt++) {
      int ct = wid*4 + nt;
      float4 bv = *(const float4*)&b2[e*H_ + ct*16 + lg*4];
      #pragma unroll
      for (int bt = 0; bt < 4; bt++) {
        float v0 = fmaxf(acc[nt][bt][0] + bv.x, 0.f);
        float v1 = fmaxf(acc[nt][bt][1] + bv.y, 0.f);
        float v2 = fmaxf(acc[nt][bt][2] + bv.z, 0.f);
        float v3 = fmaxf(acc[nt][bt][3] + bv.w, 0.f);
        int m   = 16*bt + lr;
        int byt = (32*ct + 8*lg) ^ ((m & 7) << 4);
        uint2 pkd; pkd.x = pk2(v0, v1); pkd.y = pk2(v2, v3);
        *(uint2*)((char*)sH + m*512 + byt) = pkd;
      }
    }
    __syncthreads();   // C: epi2 -> G3

    // ---- T14 write: tile B regs -> sFb (sFb readers finished at barrier A)
    if (sub == 0 && have2) {
      int chk0 = tid & 3;
      int ba = ((chk0    )*16) ^ ((row & 7) << 4);
      int bb_ = ((chk0 + 4)*16) ^ ((row & 7) << 4);
      int bc = ((chk0 + 8)*16) ^ ((row & 7) << 4);
      *(s16x8*)((char*)sFb + row*256 + ba)  = stg0;
      *(s16x8*)((char*)sFb + row*256 + bb_) = stg1;
      *(s16x8*)((char*)sFb + row*256 + bc)  = stg2;
    }

    // ========== G3^T: wave w handles bt = w ==========
    f32x4 acc3 = (f32x4){0.f,0.f,0.f,0.f};
    #pragma unroll
    for (int ks = 0; ks < 8; ks++) {
      int m = 16*wid + lr;
      int byt = (64*ks + 16*lg) ^ ((m & 7) << 4);
      s16x8 bb = *(const s16x8*)((const char*)sH + m*512 + byt);
      s16x8 a  = *(const s16x8*)(P + W3P_OFF + ((e*8 + ks) << 9) + lane*8);
      acc3 = __builtin_amdgcn_mfma_f32_16x16x32_bf16(a, bb, acc3, 0,0,0);
    }
    if (lg == 0) {
      int slot = t*64 + 16*wid + lr;
      float wv = (slot < cnt) ? wlist[e*NPTS + slot] : 0.f;
      if (wv != 0.f) {
        int p = (int)lists[e*NPTS + slot];
        #pragma unroll
        for (int r = 0; r < 4; r++)
          atomicAdd(&out[(size_t)p*DOUT + r], wv * (acc3[r] + b3[e*DOUT + r]));
      }
    }
    __syncthreads();   // D: sFb staged + sH reads done -> next sub-tile
  }
}

// ---------------- launcher --------------------------------------------------
extern "C" void kernel_launch(void* const* d_in, const int* in_sizes, int n_in,
                              void* d_out, int out_size, void* d_ws, size_t ws_size,
                              hipStream_t stream) {
  const float* x   = (const float*)d_in[0];
  const float* cen = (const float*)d_in[1];
  const float* W1  = (const float*)d_in[2];
  const float* b1  = (const float*)d_in[3];
  const float* W2  = (const float*)d_in[4];
  const float* b2  = (const float*)d_in[5];
  const float* W3  = (const float*)d_in[6];
  const float* b3  = (const float*)d_in[7];

  unsigned short* P     = (unsigned short*)d_ws;
  int*            cnts  = (int*)((char*)d_ws + CNT_OFF);
  unsigned short* lists = (unsigned short*)((char*)d_ws + LIST_OFF);
  unsigned short* XB    = (unsigned short*)((char*)d_ws + XB_OFF);
  float*          WL    = (float*)((char*)d_ws + WL_OFF);
  float* out = (float*)d_out;

  (void)hipMemsetAsync(cnts, 0, 32, stream);
  fused_prep<<<dim3(PREP_BLKS + XPK_BLKS + RC_BLKS), dim3(256), 0, stream>>>(
      x, cen, W1, W2, W3, P, (unsigned*)XB, out, cnts, lists, WL);
  expert_mlp<<<dim3(NPTS/128, E_), dim3(256), 0, stream>>>(b1, b2, b3, P, XB,
                                                           cnts, lists, WL, out);
}

// Round 15
// 107.323 us; speedup vs baseline: 1.5938x; 1.5938x over previous
//
#include <hip/hip_runtime.h>

// MegaNeRF fused MoE-MLP for MI355X (gfx950) — round 15.
// = round 10 EXACT (verified best: 101.9us total) + T5 s_setprio(1) around
// MFMA clusters in G1/G2 (independent blocks at uncorrelated phases -> MFMA
// waves get CU-scheduler priority over staging/epilogue waves; m191 regime).
// Everything else byte-identical to round 10.

typedef __attribute__((ext_vector_type(8))) short   s16x8;
typedef __attribute__((ext_vector_type(4))) float   f32x4;

#define NPTS  65536
#define E_    8
#define DIN   90
#define H_    256
#define DOUT  4

// packed weight layout: [e][ct][ks][lane][j] bf16, 512 elems per (e,ct,ks)
#define W1P_ELEMS (E_*16*3*512)   // K padded to 96 -> 3 ksteps
#define W2P_ELEMS (E_*16*8*512)   // K=256 -> 8 ksteps
#define W3P_ELEMS (E_*1*8*512)    // N padded 4->16, K=256
#define W2P_OFF   (W1P_ELEMS)
#define W3P_OFF   (W1P_ELEMS + W2P_ELEMS)
#define WSP_TOTAL (W1P_ELEMS + W2P_ELEMS + W3P_ELEMS)
#define WSP_BYTES (WSP_TOTAL*2)              // 1,507,328 B
#define CNT_OFF   WSP_BYTES                  // int[8]
#define LIST_OFF  (WSP_BYTES + 32)           // u16[E_*NPTS] = 1 MB
#define XB_OFF    (LIST_OFF + E_*NPTS*2)     // u16[NPTS*96] = 12.6 MB
#define WL_OFF    (XB_OFF + (size_t)NPTS*96*2)  // f32[E_*NPTS] = 2 MB
// total ws usage ~17.2 MB

__device__ __forceinline__ unsigned short f2bf(float f) {
  union { float f; unsigned u; } v; v.f = f;
  unsigned u = v.u;
  u += 0x7fffu + ((u >> 16) & 1u);   // round-to-nearest-even
  return (unsigned short)(u >> 16);
}
__device__ __forceinline__ unsigned pk2(float a, float b) {
  return (unsigned)f2bf(a) | ((unsigned)f2bf(b) << 16);
}

// ---------------- prep: pack W1/W2/W3 fp32 -> bf16 fragment layout ----------
__global__ void prep_pack(const float* __restrict__ W1,
                          const float* __restrict__ W2,
                          const float* __restrict__ W3,
                          unsigned short* __restrict__ P) {
  int idx = blockIdx.x * blockDim.x + threadIdx.x;
  if (idx >= WSP_TOTAL) return;
  float val;
  if (idx < W2P_OFF) {                       // W1: (e,90,256), K padded 96
    int f = idx;
    int j = f & 7, l = (f >> 3) & 63, t = f >> 9;
    int ks = t % 3; t /= 3;
    int ct = t & 15, e = t >> 4;
    int k = ks*32 + (l>>4)*8 + j;
    int n = ct*16 + (l & 15);
    val = (k < DIN) ? W1[((size_t)e*DIN + k)*H_ + n] : 0.f;
  } else if (idx < W3P_OFF) {                // W2: (e,256,256)
    int f = idx - W2P_OFF;
    int j = f & 7, l = (f >> 3) & 63, t = f >> 9;
    int ks = t & 7; t >>= 3;
    int ct = t & 15, e = t >> 4;
    int k = ks*32 + (l>>4)*8 + j;
    int n = ct*16 + (l & 15);
    val = W2[((size_t)e*H_ + k)*H_ + n];
  } else {                                   // W3: (e,256,4), N padded to 16
    int f = idx - W3P_OFF;
    int j = f & 7, l = (f >> 3) & 63, t = f >> 9;
    int ks = t & 7, e = t >> 3;
    int k = ks*32 + (l>>4)*8 + j;
    int n = l & 15;
    val = (n < DOUT) ? W3[((size_t)e*H_ + k)*DOUT + n] : 0.f;
  }
  P[idx] = f2bf(val);
}

// ---------------- prep: pack feats fp32 -> bf16 xb[N][96] -------------------
__global__ __launch_bounds__(256)
void x_pack(const float* __restrict__ x, unsigned* __restrict__ xb32) {
  int i = blockIdx.x * blockDim.x + threadIdx.x;   // one u32 (2 bf16) each
  if (i >= NPTS*48) return;
  int n = i / 48, c = i - n*48;                    // feat pair c -> dims 2c,2c+1
  const float* xr = x + (size_t)n*93 + 3;
  float v0 = (2*c   < DIN) ? xr[2*c]   : 0.f;
  float v1 = (2*c+1 < DIN) ? xr[2*c+1] : 0.f;
  xb32[(size_t)n*48 + c] = pk2(v0, v1);
}

// ---------------- routing + compaction (+ weight) into per-expert lists -----
__global__ __launch_bounds__(256)
void route_compact(const float* __restrict__ x,
                   const float* __restrict__ cen,
                   int* __restrict__ counts,
                   unsigned short* __restrict__ lists,
                   float* __restrict__ wlist) {
  const int tid = threadIdx.x;
  const int gid = blockIdx.x * 256 + tid;
  __shared__ int lcnt[E_], lbase[E_];
  if (tid < E_) lcnt[tid] = 0;
  __syncthreads();

  const float* xr = x + (size_t)gid*93;
  float px = xr[0], py = xr[1], pz = xr[2];
  float d[E_], dmin = 1e30f;
  #pragma unroll
  for (int e = 0; e < E_; e++) {
    float dx = px - cen[e*3+0], dy = py - cen[e*3+1], dz = pz - cen[e*3+2];
    d[e] = sqrtf(dx*dx + dy*dy + dz*dz);
    dmin = fminf(dmin, d[e]);
  }
  float inv[E_], s = 0.f;
  int act = 0;
  #pragma unroll
  for (int e = 0; e < E_; e++) {
    float iv = (d[e] > 2.0f*dmin) ? 0.f : 1.0f/(d[e] + 1e-8f);  // ref predicate
    inv[e] = iv; s += iv;
    if (iv > 0.f) act |= (1 << e);
  }
  float rs = 1.0f/s;
  int myoff[E_];
  #pragma unroll
  for (int e = 0; e < E_; e++)
    if ((act >> e) & 1) myoff[e] = atomicAdd(&lcnt[e], 1);
  __syncthreads();
  if (tid < E_) lbase[tid] = atomicAdd(&counts[tid], lcnt[tid]);
  __syncthreads();
  #pragma unroll
  for (int e = 0; e < E_; e++)
    if ((act >> e) & 1) {
      int slot = e*NPTS + lbase[e] + myoff[e];
      lists[slot] = (unsigned short)gid;
      wlist[slot] = inv[e]*rs;
    }
}

// ---------------- per-expert transposed MLP, 64 points per block ------------
__global__ __launch_bounds__(256, 3)
void expert_mlp(const float* __restrict__ b1,
                const float* __restrict__ b2,
                const float* __restrict__ b3,
                const unsigned short* __restrict__ P,
                const unsigned short* __restrict__ XB,
                const int* __restrict__ counts,
                const unsigned short* __restrict__ lists,
                const float* __restrict__ wlist,
                float* __restrict__ out) {
  const int e   = blockIdx.y;
  const int cnt = counts[e];
  const int t   = blockIdx.x;
  if (t*64 >= cnt) return;

  __shared__ __attribute__((aligned(16))) unsigned short sFb[64*128]; // 16KB
  __shared__ __attribute__((aligned(16))) unsigned short sH[64*256];  // 32KB

  const int tid  = threadIdx.x;
  const int wid  = tid >> 6;
  const int lane = tid & 63;
  const int lg   = lane >> 4;
  const int lr   = lane & 15;

  // ---- stage the 64-row feats tile ONCE (shared by all 4 waves).
  {
    int row  = tid >> 2;
    int slot = t*64 + row;
    int p    = (slot < cnt) ? (int)lists[e*NPTS + slot] : 0;
    const unsigned short* src = XB + (size_t)p*96;
    #pragma unroll
    for (int it = 0; it < 3; it++) {
      int chk = (tid & 3) + 4*it;
      s16x8 v = *(const s16x8*)(src + chk*8);
      int byt = (chk*16) ^ ((row & 7) << 4);
      *(s16x8*)((char*)sFb + row*256 + byt) = v;
    }
  }
  __syncthreads();

  f32x4 acc[4][4];   // [nt][bt]
  // ========== G1^T: h1^T = W1^T @ feats^T, K=96 (B-frags from sFb) ==========
  #pragma unroll
  for (int nt = 0; nt < 4; nt++)
    #pragma unroll
    for (int bt = 0; bt < 4; bt++) acc[nt][bt] = (f32x4){0.f,0.f,0.f,0.f};

  {
    const unsigned short* PW1 = P + (((e*16 + wid*4)*3) << 9) + lane*8;
    #pragma unroll
    for (int ks = 0; ks < 3; ks++) {
      s16x8 bfr[4];
      #pragma unroll
      for (int bt = 0; bt < 4; bt++) {
        int m = 16*bt + lr;
        int byt = (64*ks + 16*lg) ^ ((m & 7) << 4);
        bfr[bt] = *(const s16x8*)((const char*)sFb + m*256 + byt);
      }
      __builtin_amdgcn_s_setprio(1);
      #pragma unroll
      for (int nt = 0; nt < 4; nt++) {
        s16x8 a = *(const s16x8*)(PW1 + ((nt*3 + ks) << 9));
        #pragma unroll
        for (int bt = 0; bt < 4; bt++)
          acc[nt][bt] = __builtin_amdgcn_mfma_f32_16x16x32_bf16(a, bfr[bt], acc[nt][bt], 0,0,0);
      }
      __builtin_amdgcn_s_setprio(0);
    }
  }

  // epilogue 1: bias+relu, pack, 8B write to sH (m-major, k-contig, XOR swz)
  #pragma unroll
  for (int nt = 0; nt < 4; nt++) {
    int ct = wid*4 + nt;
    float4 bv = *(const float4*)&b1[e*H_ + ct*16 + lg*4];
    #pragma unroll
    for (int bt = 0; bt < 4; bt++) {
      float v0 = fmaxf(acc[nt][bt][0] + bv.x, 0.f);
      float v1 = fmaxf(acc[nt][bt][1] + bv.y, 0.f);
      float v2 = fmaxf(acc[nt][bt][2] + bv.z, 0.f);
      float v3 = fmaxf(acc[nt][bt][3] + bv.w, 0.f);
      int m   = 16*bt + lr;
      int byt = (32*ct + 8*lg) ^ ((m & 7) << 4);
      uint2 pkd; pkd.x = pk2(v0, v1); pkd.y = pk2(v2, v3);
      *(uint2*)((char*)sH + m*512 + byt) = pkd;
    }
  }
  __syncthreads();

  // ========== G2^T: h2^T = W2^T @ h1^T, K=256 ==========
  #pragma unroll
  for (int nt = 0; nt < 4; nt++)
    #pragma unroll
    for (int bt = 0; bt < 4; bt++) acc[nt][bt] = (f32x4){0.f,0.f,0.f,0.f};

  {
    const unsigned short* PW2 = P + W2P_OFF + (((e*16 + wid*4)*8) << 9) + lane*8;
    #pragma unroll
    for (int ks = 0; ks < 8; ks++) {
      s16x8 bfr[4];
      #pragma unroll
      for (int bt = 0; bt < 4; bt++) {
        int m = 16*bt + lr;
        int byt = (64*ks + 16*lg) ^ ((m & 7) << 4);
        bfr[bt] = *(const s16x8*)((const char*)sH + m*512 + byt);
      }
      __builtin_amdgcn_s_setprio(1);
      #pragma unroll
      for (int nt = 0; nt < 4; nt++) {
        s16x8 a = *(const s16x8*)(PW2 + ((nt*8 + ks) << 9));
        #pragma unroll
        for (int bt = 0; bt < 4; bt++)
          acc[nt][bt] = __builtin_amdgcn_mfma_f32_16x16x32_bf16(a, bfr[bt], acc[nt][bt], 0,0,0);
      }
      __builtin_amdgcn_s_setprio(0);
    }
  }
  __syncthreads();   // all G2 reads of h1 complete

  // epilogue 2: bias+relu -> sH (h2)
  #pragma unroll
  for (int nt = 0; nt < 4; nt++) {
    int ct = wid*4 + nt;
    float4 bv = *(const float4*)&b2[e*H_ + ct*16 + lg*4];
    #pragma unroll
    for (int bt = 0; bt < 4; bt++) {
      float v0 = fmaxf(acc[nt][bt][0] + bv.x, 0.f);
      float v1 = fmaxf(acc[nt][bt][1] + bv.y, 0.f);
      float v2 = fmaxf(acc[nt][bt][2] + bv.z, 0.f);
      float v3 = fmaxf(acc[nt][bt][3] + bv.w, 0.f);
      int m   = 16*bt + lr;
      int byt = (32*ct + 8*lg) ^ ((m & 7) << 4);
      uint2 pkd; pkd.x = pk2(v0, v1); pkd.y = pk2(v2, v3);
      *(uint2*)((char*)sH + m*512 + byt) = pkd;
    }
  }
  __syncthreads();

  // ========== G3^T: out^T = W3^T @ h2^T (n3 padded to 16), wave w: bt=w =====
  f32x4 acc3 = (f32x4){0.f,0.f,0.f,0.f};
  #pragma unroll
  for (int ks = 0; ks < 8; ks++) {
    int m = 16*wid + lr;
    int byt = (64*ks + 16*lg) ^ ((m & 7) << 4);
    s16x8 bb = *(const s16x8*)((const char*)sH + m*512 + byt);
    s16x8 a  = *(const s16x8*)(P + W3P_OFF + ((e*8 + ks) << 9) + lane*8);
    acc3 = __builtin_amdgcn_mfma_f32_16x16x32_bf16(a, bb, acc3, 0,0,0);
  }

  // lane (lg=0, lr): rows n3=0..3 of point m=16*wid+lr
  if (lg == 0) {
    int slot = t*64 + 16*wid + lr;
    float wv = (slot < cnt) ? wlist[e*NPTS + slot] : 0.f;
    if (wv != 0.f) {
      int p = (int)lists[e*NPTS + slot];
      #pragma unroll
      for (int r = 0; r < 4; r++)
        atomicAdd(&out[(size_t)p*DOUT + r], wv * (acc3[r] + b3[e*DOUT + r]));
    }
  }
}

// ---------------- launcher --------------------------------------------------
extern "C" void kernel_launch(void* const* d_in, const int* in_sizes, int n_in,
                              void* d_out, int out_size, void* d_ws, size_t ws_size,
                              hipStream_t stream) {
  const float* x   = (const float*)d_in[0];
  const float* cen = (const float*)d_in[1];
  const float* W1  = (const float*)d_in[2];
  const float* b1  = (const float*)d_in[3];
  const float* W2  = (const float*)d_in[4];
  const float* b2  = (const float*)d_in[5];
  const float* W3  = (const float*)d_in[6];
  const float* b3  = (const float*)d_in[7];

  unsigned short* P     = (unsigned short*)d_ws;
  int*            cnts  = (int*)((char*)d_ws + CNT_OFF);
  unsigned short* lists = (unsigned short*)((char*)d_ws + LIST_OFF);
  unsigned short* XB    = (unsigned short*)((char*)d_ws + XB_OFF);
  float*          WL    = (float*)((char*)d_ws + WL_OFF);
  float* out = (float*)d_out;

  (void)hipMemsetAsync(cnts, 0, 32, stream);
  (void)hipMemsetAsync(out, 0, (size_t)NPTS*DOUT*sizeof(float), stream);
  prep_pack<<<dim3((WSP_TOTAL + 255)/256), dim3(256), 0, stream>>>(W1, W2, W3, P);
  x_pack<<<dim3((NPTS*48 + 255)/256), dim3(256), 0, stream>>>(x, (unsigned*)XB);
  route_compact<<<dim3(NPTS/256), dim3(256), 0, stream>>>(x, cen, cnts, lists, WL);
  expert_mlp<<<dim3(NPTS/64, E_), dim3(256), 0, stream>>>(b1, b2, b3, P, XB,
                                                          cnts, lists, WL, out);
}

// Round 16
// 95.237 us; speedup vs baseline: 1.7960x; 1.1269x over previous
//
#include <hip/hip_runtime.h>

// MegaNeRF fused MoE-MLP for MI355X (gfx950) — round 16: consolidation.
// expert_mlp = round 10 EXACT (best verified: ~85us dispatch; pk2 packing,
// no setprio — r15 showed setprio null in this barrier-lockstep structure).
// Prep chain = r13's verified fused_prep (3 independent roles in one kernel;
// r13's regression was the cvtpk inside expert_mlp, not the prep fusion).
// 2 enqueues + 1 memset total.

typedef __attribute__((ext_vector_type(8))) short   s16x8;
typedef __attribute__((ext_vector_type(4))) float   f32x4;

#define NPTS  65536
#define E_    8
#define DIN   90
#define H_    256
#define DOUT  4

// packed weight layout: [e][ct][ks][lane][j] bf16, 512 elems per (e,ct,ks)
#define W1P_ELEMS (E_*16*3*512)   // 196608
#define W2P_ELEMS (E_*16*8*512)   // 524288
#define W3P_ELEMS (E_*1*8*512)    // 32768
#define W2P_OFF   (W1P_ELEMS)
#define W3P_OFF   (W1P_ELEMS + W2P_ELEMS)
#define WSP_TOTAL (W1P_ELEMS + W2P_ELEMS + W3P_ELEMS)   // 753664
#define WSP_BYTES (WSP_TOTAL*2)
#define CNT_OFF   WSP_BYTES                  // int[8]
#define LIST_OFF  (WSP_BYTES + 32)           // u16[E_*NPTS] = 1 MB
#define XB_OFF    (LIST_OFF + E_*NPTS*2)     // u16[NPTS*96] = 12.6 MB
#define WL_OFF    (XB_OFF + (size_t)NPTS*96*2)  // f32[E_*NPTS] = 2 MB
// total ws usage ~17.2 MB

// fused-prep block ranges (256 threads each)
#define PREP_BLKS (WSP_TOTAL/256)            // 2944 (exact)
#define XPK_BLKS  (NPTS*48/256)              // 12288 (exact)
#define RC_BLKS   (NPTS/256)                 // 256

__device__ __forceinline__ unsigned short f2bf(float f) {
  union { float f; unsigned u; } v; v.f = f;
  unsigned u = v.u;
  u += 0x7fffu + ((u >> 16) & 1u);   // round-to-nearest-even
  return (unsigned short)(u >> 16);
}
__device__ __forceinline__ unsigned pk2(float a, float b) {
  return (unsigned)f2bf(a) | ((unsigned)f2bf(b) << 16);
}

// ---------------- fused prep: weights-pack | x-pack+out-zero | route --------
__global__ __launch_bounds__(256)
void fused_prep(const float* __restrict__ x,
                const float* __restrict__ cen,
                const float* __restrict__ W1,
                const float* __restrict__ W2,
                const float* __restrict__ W3,
                unsigned short* __restrict__ P,
                unsigned* __restrict__ xb32,
                float* __restrict__ out,
                int* __restrict__ counts,
                unsigned short* __restrict__ lists,
                float* __restrict__ wlist) {
  const int b   = blockIdx.x;
  const int tid = threadIdx.x;

  if (b < PREP_BLKS) {
    // ---- role 1: pack W1/W2/W3 fp32 -> bf16 fragment layout
    int idx = b*256 + tid;
    float val;
    if (idx < W2P_OFF) {                       // W1: (e,90,256), K padded 96
      int f = idx;
      int j = f & 7, l = (f >> 3) & 63, t = f >> 9;
      int ks = t % 3; t /= 3;
      int ct = t & 15, e = t >> 4;
      int k = ks*32 + (l>>4)*8 + j;
      int n = ct*16 + (l & 15);
      val = (k < DIN) ? W1[((size_t)e*DIN + k)*H_ + n] : 0.f;
    } else if (idx < W3P_OFF) {                // W2: (e,256,256)
      int f = idx - W2P_OFF;
      int j = f & 7, l = (f >> 3) & 63, t = f >> 9;
      int ks = t & 7; t >>= 3;
      int ct = t & 15, e = t >> 4;
      int k = ks*32 + (l>>4)*8 + j;
      int n = ct*16 + (l & 15);
      val = W2[((size_t)e*H_ + k)*H_ + n];
    } else {                                   // W3: (e,256,4), N padded to 16
      int f = idx - W3P_OFF;
      int j = f & 7, l = (f >> 3) & 63, t = f >> 9;
      int ks = t & 7, e = t >> 3;
      int k = ks*32 + (l>>4)*8 + j;
      int n = l & 15;
      val = (n < DOUT) ? W3[((size_t)e*H_ + k)*DOUT + n] : 0.f;
    }
    P[idx] = f2bf(val);

  } else if (b < PREP_BLKS + XPK_BLKS) {
    // ---- role 2: pack feats fp32 -> bf16 xb[N][96]; zero out
    int i = (b - PREP_BLKS)*256 + tid;
    if (i < NPTS*DOUT) out[i] = 0.f;
    int n = i / 48, c = i - n*48;
    const float* xr = x + (size_t)n*93 + 3;
    float v0 = (2*c   < DIN) ? xr[2*c]   : 0.f;
    float v1 = (2*c+1 < DIN) ? xr[2*c+1] : 0.f;
    xb32[(size_t)n*48 + c] = pk2(v0, v1);

  } else {
    // ---- role 3: routing + compaction (+ weight)
    int gid = (b - PREP_BLKS - XPK_BLKS)*256 + tid;
    __shared__ int lcnt[E_], lbase[E_];
    if (tid < E_) lcnt[tid] = 0;
    __syncthreads();

    const float* xr = x + (size_t)gid*93;
    float px = xr[0], py = xr[1], pz = xr[2];
    float d[E_], dmin = 1e30f;
    #pragma unroll
    for (int e = 0; e < E_; e++) {
      float dx = px - cen[e*3+0], dy = py - cen[e*3+1], dz = pz - cen[e*3+2];
      d[e] = sqrtf(dx*dx + dy*dy + dz*dz);
      dmin = fminf(dmin, d[e]);
    }
    float inv[E_], s = 0.f;
    int act = 0;
    #pragma unroll
    for (int e = 0; e < E_; e++) {
      float iv = (d[e] > 2.0f*dmin) ? 0.f : 1.0f/(d[e] + 1e-8f);  // ref predicate
      inv[e] = iv; s += iv;
      if (iv > 0.f) act |= (1 << e);
    }
    float rs = 1.0f/s;
    int myoff[E_];
    #pragma unroll
    for (int e = 0; e < E_; e++)
      if ((act >> e) & 1) myoff[e] = atomicAdd(&lcnt[e], 1);
    __syncthreads();
    if (tid < E_) lbase[tid] = atomicAdd(&counts[tid], lcnt[tid]);
    __syncthreads();
    #pragma unroll
    for (int e = 0; e < E_; e++)
      if ((act >> e) & 1) {
        int slot = e*NPTS + lbase[e] + myoff[e];
        lists[slot] = (unsigned short)gid;
        wlist[slot] = inv[e]*rs;
      }
  }
}

// ---------------- per-expert transposed MLP, 64 points per block ------------
__global__ __launch_bounds__(256, 3)
void expert_mlp(const float* __restrict__ b1,
                const float* __restrict__ b2,
                const float* __restrict__ b3,
                const unsigned short* __restrict__ P,
                const unsigned short* __restrict__ XB,
                const int* __restrict__ counts,
                const unsigned short* __restrict__ lists,
                const float* __restrict__ wlist,
                float* __restrict__ out) {
  const int e   = blockIdx.y;
  const int cnt = counts[e];
  const int t   = blockIdx.x;
  if (t*64 >= cnt) return;

  __shared__ __attribute__((aligned(16))) unsigned short sFb[64*128]; // 16KB
  __shared__ __attribute__((aligned(16))) unsigned short sH[64*256];  // 32KB

  const int tid  = threadIdx.x;
  const int wid  = tid >> 6;
  const int lane = tid & 63;
  const int lg   = lane >> 4;
  const int lr   = lane & 15;

  // ---- stage the 64-row feats tile ONCE (shared by all 4 waves).
  {
    int row  = tid >> 2;
    int slot = t*64 + row;
    int p    = (slot < cnt) ? (int)lists[e*NPTS + slot] : 0;
    const unsigned short* src = XB + (size_t)p*96;
    #pragma unroll
    for (int it = 0; it < 3; it++) {
      int chk = (tid & 3) + 4*it;
      s16x8 v = *(const s16x8*)(src + chk*8);
      int byt = (chk*16) ^ ((row & 7) << 4);
      *(s16x8*)((char*)sFb + row*256 + byt) = v;
    }
  }
  __syncthreads();

  f32x4 acc[4][4];   // [nt][bt]
  // ========== G1^T: h1^T = W1^T @ feats^T, K=96 (B-frags from sFb) ==========
  #pragma unroll
  for (int nt = 0; nt < 4; nt++)
    #pragma unroll
    for (int bt = 0; bt < 4; bt++) acc[nt][bt] = (f32x4){0.f,0.f,0.f,0.f};

  {
    const unsigned short* PW1 = P + (((e*16 + wid*4)*3) << 9) + lane*8;
    #pragma unroll
    for (int ks = 0; ks < 3; ks++) {
      s16x8 bfr[4];
      #pragma unroll
      for (int bt = 0; bt < 4; bt++) {
        int m = 16*bt + lr;
        int byt = (64*ks + 16*lg) ^ ((m & 7) << 4);
        bfr[bt] = *(const s16x8*)((const char*)sFb + m*256 + byt);
      }
      #pragma unroll
      for (int nt = 0; nt < 4; nt++) {
        s16x8 a = *(const s16x8*)(PW1 + ((nt*3 + ks) << 9));
        #pragma unroll
        for (int bt = 0; bt < 4; bt++)
          acc[nt][bt] = __builtin_amdgcn_mfma_f32_16x16x32_bf16(a, bfr[bt], acc[nt][bt], 0,0,0);
      }
    }
  }

  // epilogue 1: bias+relu, pack, 8B write to sH (m-major, k-contig, XOR swz)
  #pragma unroll
  for (int nt = 0; nt < 4; nt++) {
    int ct = wid*4 + nt;
    float4 bv = *(const float4*)&b1[e*H_ + ct*16 + lg*4];
    #pragma unroll
    for (int bt = 0; bt < 4; bt++) {
      float v0 = fmaxf(acc[nt][bt][0] + bv.x, 0.f);
      float v1 = fmaxf(acc[nt][bt][1] + bv.y, 0.f);
      float v2 = fmaxf(acc[nt][bt][2] + bv.z, 0.f);
      float v3 = fmaxf(acc[nt][bt][3] + bv.w, 0.f);
      int m   = 16*bt + lr;
      int byt = (32*ct + 8*lg) ^ ((m & 7) << 4);
      uint2 pkd; pkd.x = pk2(v0, v1); pkd.y = pk2(v2, v3);
      *(uint2*)((char*)sH + m*512 + byt) = pkd;
    }
  }
  __syncthreads();

  // ========== G2^T: h2^T = W2^T @ h1^T, K=256 ==========
  #pragma unroll
  for (int nt = 0; nt < 4; nt++)
    #pragma unroll
    for (int bt = 0; bt < 4; bt++) acc[nt][bt] = (f32x4){0.f,0.f,0.f,0.f};

  {
    const unsigned short* PW2 = P + W2P_OFF + (((e*16 + wid*4)*8) << 9) + lane*8;
    #pragma unroll
    for (int ks = 0; ks < 8; ks++) {
      s16x8 bfr[4];
      #pragma unroll
      for (int bt = 0; bt < 4; bt++) {
        int m = 16*bt + lr;
        int byt = (64*ks + 16*lg) ^ ((m & 7) << 4);
        bfr[bt] = *(const s16x8*)((const char*)sH + m*512 + byt);
      }
      #pragma unroll
      for (int nt = 0; nt < 4; nt++) {
        s16x8 a = *(const s16x8*)(PW2 + ((nt*8 + ks) << 9));
        #pragma unroll
        for (int bt = 0; bt < 4; bt++)
          acc[nt][bt] = __builtin_amdgcn_mfma_f32_16x16x32_bf16(a, bfr[bt], acc[nt][bt], 0,0,0);
      }
    }
  }
  __syncthreads();   // all G2 reads of h1 complete

  // epilogue 2: bias+relu -> sH (h2)
  #pragma unroll
  for (int nt = 0; nt < 4; nt++) {
    int ct = wid*4 + nt;
    float4 bv = *(const float4*)&b2[e*H_ + ct*16 + lg*4];
    #pragma unroll
    for (int bt = 0; bt < 4; bt++) {
      float v0 = fmaxf(acc[nt][bt][0] + bv.x, 0.f);
      float v1 = fmaxf(acc[nt][bt][1] + bv.y, 0.f);
      float v2 = fmaxf(acc[nt][bt][2] + bv.z, 0.f);
      float v3 = fmaxf(acc[nt][bt][3] + bv.w, 0.f);
      int m   = 16*bt + lr;
      int byt = (32*ct + 8*lg) ^ ((m & 7) << 4);
      uint2 pkd; pkd.x = pk2(v0, v1); pkd.y = pk2(v2, v3);
      *(uint2*)((char*)sH + m*512 + byt) = pkd;
    }
  }
  __syncthreads();

  // ========== G3^T: out^T = W3^T @ h2^T (n3 padded to 16), wave w: bt=w =====
  f32x4 acc3 = (f32x4){0.f,0.f,0.f,0.f};
  #pragma unroll
  for (int ks = 0; ks < 8; ks++) {
    int m = 16*wid + lr;
    int byt = (64*ks + 16*lg) ^ ((m & 7) << 4);
    s16x8 bb = *(const s16x8*)((const char*)sH + m*512 + byt);
    s16x8 a  = *(const s16x8*)(P + W3P_OFF + ((e*8 + ks) << 9) + lane*8);
    acc3 = __builtin_amdgcn_mfma_f32_16x16x32_bf16(a, bb, acc3, 0,0,0);
  }

  // lane (lg=0, lr): rows n3=0..3 of point m=16*wid+lr
  if (lg == 0) {
    int slot = t*64 + 16*wid + lr;
    float wv = (slot < cnt) ? wlist[e*NPTS + slot] : 0.f;
    if (wv != 0.f) {
      int p = (int)lists[e*NPTS + slot];
      #pragma unroll
      for (int r = 0; r < 4; r++)
        atomicAdd(&out[(size_t)p*DOUT + r], wv * (acc3[r] + b3[e*DOUT + r]));
    }
  }
}

// ---------------- launcher --------------------------------------------------
extern "C" void kernel_launch(void* const* d_in, const int* in_sizes, int n_in,
                              void* d_out, int out_size, void* d_ws, size_t ws_size,
                              hipStream_t stream) {
  const float* x   = (const float*)d_in[0];
  const float* cen = (const float*)d_in[1];
  const float* W1  = (const float*)d_in[2];
  const float* b1  = (const float*)d_in[3];
  const float* W2  = (const float*)d_in[4];
  const float* b2  = (const float*)d_in[5];
  const float* W3  = (const float*)d_in[6];
  const float* b3  = (const float*)d_in[7];

  unsigned short* P     = (unsigned short*)d_ws;
  int*            cnts  = (int*)((char*)d_ws + CNT_OFF);
  unsigned short* lists = (unsigned short*)((char*)d_ws + LIST_OFF);
  unsigned short* XB    = (unsigned short*)((char*)d_ws + XB_OFF);
  float*          WL    = (float*)((char*)d_ws + WL_OFF);
  float* out = (float*)d_out;

  (void)hipMemsetAsync(cnts, 0, 32, stream);
  fused_prep<<<dim3(PREP_BLKS + XPK_BLKS + RC_BLKS), dim3(256), 0, stream>>>(
      x, cen, W1, W2, W3, P, (unsigned*)XB, out, cnts, lists, WL);
  expert_mlp<<<dim3(NPTS/64, E_), dim3(256), 0, stream>>>(b1, b2, b3, P, XB,
                                                          cnts, lists, WL, out);
}

// Round 17
// 94.984 us; speedup vs baseline: 1.8008x; 1.0027x over previous
//
#include <hip/hip_runtime.h>

// MegaNeRF fused MoE-MLP for MI355X (gfx950) — round 17 = round 16 VERBATIM.
// Variance-confirmation run of the session-best configuration (95.2us total):
// fused prep (3 roles, 1 kernel) + expert_mlp (64pt/4w, transposed dataflow,
// LDS-staged feats, XOR-swizzled sH, pk2 packing, no setprio).

typedef __attribute__((ext_vector_type(8))) short   s16x8;
typedef __attribute__((ext_vector_type(4))) float   f32x4;

#define NPTS  65536
#define E_    8
#define DIN   90
#define H_    256
#define DOUT  4

// packed weight layout: [e][ct][ks][lane][j] bf16, 512 elems per (e,ct,ks)
#define W1P_ELEMS (E_*16*3*512)   // 196608
#define W2P_ELEMS (E_*16*8*512)   // 524288
#define W3P_ELEMS (E_*1*8*512)    // 32768
#define W2P_OFF   (W1P_ELEMS)
#define W3P_OFF   (W1P_ELEMS + W2P_ELEMS)
#define WSP_TOTAL (W1P_ELEMS + W2P_ELEMS + W3P_ELEMS)   // 753664
#define WSP_BYTES (WSP_TOTAL*2)
#define CNT_OFF   WSP_BYTES                  // int[8]
#define LIST_OFF  (WSP_BYTES + 32)           // u16[E_*NPTS] = 1 MB
#define XB_OFF    (LIST_OFF + E_*NPTS*2)     // u16[NPTS*96] = 12.6 MB
#define WL_OFF    (XB_OFF + (size_t)NPTS*96*2)  // f32[E_*NPTS] = 2 MB
// total ws usage ~17.2 MB

// fused-prep block ranges (256 threads each)
#define PREP_BLKS (WSP_TOTAL/256)            // 2944 (exact)
#define XPK_BLKS  (NPTS*48/256)              // 12288 (exact)
#define RC_BLKS   (NPTS/256)                 // 256

__device__ __forceinline__ unsigned short f2bf(float f) {
  union { float f; unsigned u; } v; v.f = f;
  unsigned u = v.u;
  u += 0x7fffu + ((u >> 16) & 1u);   // round-to-nearest-even
  return (unsigned short)(u >> 16);
}
__device__ __forceinline__ unsigned pk2(float a, float b) {
  return (unsigned)f2bf(a) | ((unsigned)f2bf(b) << 16);
}

// ---------------- fused prep: weights-pack | x-pack+out-zero | route --------
__global__ __launch_bounds__(256)
void fused_prep(const float* __restrict__ x,
                const float* __restrict__ cen,
                const float* __restrict__ W1,
                const float* __restrict__ W2,
                const float* __restrict__ W3,
                unsigned short* __restrict__ P,
                unsigned* __restrict__ xb32,
                float* __restrict__ out,
                int* __restrict__ counts,
                unsigned short* __restrict__ lists,
                float* __restrict__ wlist) {
  const int b   = blockIdx.x;
  const int tid = threadIdx.x;

  if (b < PREP_BLKS) {
    // ---- role 1: pack W1/W2/W3 fp32 -> bf16 fragment layout
    int idx = b*256 + tid;
    float val;
    if (idx < W2P_OFF) {                       // W1: (e,90,256), K padded 96
      int f = idx;
      int j = f & 7, l = (f >> 3) & 63, t = f >> 9;
      int ks = t % 3; t /= 3;
      int ct = t & 15, e = t >> 4;
      int k = ks*32 + (l>>4)*8 + j;
      int n = ct*16 + (l & 15);
      val = (k < DIN) ? W1[((size_t)e*DIN + k)*H_ + n] : 0.f;
    } else if (idx < W3P_OFF) {                // W2: (e,256,256)
      int f = idx - W2P_OFF;
      int j = f & 7, l = (f >> 3) & 63, t = f >> 9;
      int ks = t & 7; t >>= 3;
      int ct = t & 15, e = t >> 4;
      int k = ks*32 + (l>>4)*8 + j;
      int n = ct*16 + (l & 15);
      val = W2[((size_t)e*H_ + k)*H_ + n];
    } else {                                   // W3: (e,256,4), N padded to 16
      int f = idx - W3P_OFF;
      int j = f & 7, l = (f >> 3) & 63, t = f >> 9;
      int ks = t & 7, e = t >> 3;
      int k = ks*32 + (l>>4)*8 + j;
      int n = l & 15;
      val = (n < DOUT) ? W3[((size_t)e*H_ + k)*DOUT + n] : 0.f;
    }
    P[idx] = f2bf(val);

  } else if (b < PREP_BLKS + XPK_BLKS) {
    // ---- role 2: pack feats fp32 -> bf16 xb[N][96]; zero out
    int i = (b - PREP_BLKS)*256 + tid;
    if (i < NPTS*DOUT) out[i] = 0.f;
    int n = i / 48, c = i - n*48;
    const float* xr = x + (size_t)n*93 + 3;
    float v0 = (2*c   < DIN) ? xr[2*c]   : 0.f;
    float v1 = (2*c+1 < DIN) ? xr[2*c+1] : 0.f;
    xb32[(size_t)n*48 + c] = pk2(v0, v1);

  } else {
    // ---- role 3: routing + compaction (+ weight)
    int gid = (b - PREP_BLKS - XPK_BLKS)*256 + tid;
    __shared__ int lcnt[E_], lbase[E_];
    if (tid < E_) lcnt[tid] = 0;
    __syncthreads();

    const float* xr = x + (size_t)gid*93;
    float px = xr[0], py = xr[1], pz = xr[2];
    float d[E_], dmin = 1e30f;
    #pragma unroll
    for (int e = 0; e < E_; e++) {
      float dx = px - cen[e*3+0], dy = py - cen[e*3+1], dz = pz - cen[e*3+2];
      d[e] = sqrtf(dx*dx + dy*dy + dz*dz);
      dmin = fminf(dmin, d[e]);
    }
    float inv[E_], s = 0.f;
    int act = 0;
    #pragma unroll
    for (int e = 0; e < E_; e++) {
      float iv = (d[e] > 2.0f*dmin) ? 0.f : 1.0f/(d[e] + 1e-8f);  // ref predicate
      inv[e] = iv; s += iv;
      if (iv > 0.f) act |= (1 << e);
    }
    float rs = 1.0f/s;
    int myoff[E_];
    #pragma unroll
    for (int e = 0; e < E_; e++)
      if ((act >> e) & 1) myoff[e] = atomicAdd(&lcnt[e], 1);
    __syncthreads();
    if (tid < E_) lbase[tid] = atomicAdd(&counts[tid], lcnt[tid]);
    __syncthreads();
    #pragma unroll
    for (int e = 0; e < E_; e++)
      if ((act >> e) & 1) {
        int slot = e*NPTS + lbase[e] + myoff[e];
        lists[slot] = (unsigned short)gid;
        wlist[slot] = inv[e]*rs;
      }
  }
}

// ---------------- per-expert transposed MLP, 64 points per block ------------
__global__ __launch_bounds__(256, 3)
void expert_mlp(const float* __restrict__ b1,
                const float* __restrict__ b2,
                const float* __restrict__ b3,
                const unsigned short* __restrict__ P,
                const unsigned short* __restrict__ XB,
                const int* __restrict__ counts,
                const unsigned short* __restrict__ lists,
                const float* __restrict__ wlist,
                float* __restrict__ out) {
  const int e   = blockIdx.y;
  const int cnt = counts[e];
  const int t   = blockIdx.x;
  if (t*64 >= cnt) return;

  __shared__ __attribute__((aligned(16))) unsigned short sFb[64*128]; // 16KB
  __shared__ __attribute__((aligned(16))) unsigned short sH[64*256];  // 32KB

  const int tid  = threadIdx.x;
  const int wid  = tid >> 6;
  const int lane = tid & 63;
  const int lg   = lane >> 4;
  const int lr   = lane & 15;

  // ---- stage the 64-row feats tile ONCE (shared by all 4 waves).
  {
    int row  = tid >> 2;
    int slot = t*64 + row;
    int p    = (slot < cnt) ? (int)lists[e*NPTS + slot] : 0;
    const unsigned short* src = XB + (size_t)p*96;
    #pragma unroll
    for (int it = 0; it < 3; it++) {
      int chk = (tid & 3) + 4*it;
      s16x8 v = *(const s16x8*)(src + chk*8);
      int byt = (chk*16) ^ ((row & 7) << 4);
      *(s16x8*)((char*)sFb + row*256 + byt) = v;
    }
  }
  __syncthreads();

  f32x4 acc[4][4];   // [nt][bt]
  // ========== G1^T: h1^T = W1^T @ feats^T, K=96 (B-frags from sFb) ==========
  #pragma unroll
  for (int nt = 0; nt < 4; nt++)
    #pragma unroll
    for (int bt = 0; bt < 4; bt++) acc[nt][bt] = (f32x4){0.f,0.f,0.f,0.f};

  {
    const unsigned short* PW1 = P + (((e*16 + wid*4)*3) << 9) + lane*8;
    #pragma unroll
    for (int ks = 0; ks < 3; ks++) {
      s16x8 bfr[4];
      #pragma unroll
      for (int bt = 0; bt < 4; bt++) {
        int m = 16*bt + lr;
        int byt = (64*ks + 16*lg) ^ ((m & 7) << 4);
        bfr[bt] = *(const s16x8*)((const char*)sFb + m*256 + byt);
      }
      #pragma unroll
      for (int nt = 0; nt < 4; nt++) {
        s16x8 a = *(const s16x8*)(PW1 + ((nt*3 + ks) << 9));
        #pragma unroll
        for (int bt = 0; bt < 4; bt++)
          acc[nt][bt] = __builtin_amdgcn_mfma_f32_16x16x32_bf16(a, bfr[bt], acc[nt][bt], 0,0,0);
      }
    }
  }

  // epilogue 1: bias+relu, pack, 8B write to sH (m-major, k-contig, XOR swz)
  #pragma unroll
  for (int nt = 0; nt < 4; nt++) {
    int ct = wid*4 + nt;
    float4 bv = *(const float4*)&b1[e*H_ + ct*16 + lg*4];
    #pragma unroll
    for (int bt = 0; bt < 4; bt++) {
      float v0 = fmaxf(acc[nt][bt][0] + bv.x, 0.f);
      float v1 = fmaxf(acc[nt][bt][1] + bv.y, 0.f);
      float v2 = fmaxf(acc[nt][bt][2] + bv.z, 0.f);
      float v3 = fmaxf(acc[nt][bt][3] + bv.w, 0.f);
      int m   = 16*bt + lr;
      int byt = (32*ct + 8*lg) ^ ((m & 7) << 4);
      uint2 pkd; pkd.x = pk2(v0, v1); pkd.y = pk2(v2, v3);
      *(uint2*)((char*)sH + m*512 + byt) = pkd;
    }
  }
  __syncthreads();

  // ========== G2^T: h2^T = W2^T @ h1^T, K=256 ==========
  #pragma unroll
  for (int nt = 0; nt < 4; nt++)
    #pragma unroll
    for (int bt = 0; bt < 4; bt++) acc[nt][bt] = (f32x4){0.f,0.f,0.f,0.f};

  {
    const unsigned short* PW2 = P + W2P_OFF + (((e*16 + wid*4)*8) << 9) + lane*8;
    #pragma unroll
    for (int ks = 0; ks < 8; ks++) {
      s16x8 bfr[4];
      #pragma unroll
      for (int bt = 0; bt < 4; bt++) {
        int m = 16*bt + lr;
        int byt = (64*ks + 16*lg) ^ ((m & 7) << 4);
        bfr[bt] = *(const s16x8*)((const char*)sH + m*512 + byt);
      }
      #pragma unroll
      for (int nt = 0; nt < 4; nt++) {
        s16x8 a = *(const s16x8*)(PW2 + ((nt*8 + ks) << 9));
        #pragma unroll
        for (int bt = 0; bt < 4; bt++)
          acc[nt][bt] = __builtin_amdgcn_mfma_f32_16x16x32_bf16(a, bfr[bt], acc[nt][bt], 0,0,0);
      }
    }
  }
  __syncthreads();   // all G2 reads of h1 complete

  // epilogue 2: bias+relu -> sH (h2)
  #pragma unroll
  for (int nt = 0; nt < 4; nt++) {
    int ct = wid*4 + nt;
    float4 bv = *(const float4*)&b2[e*H_ + ct*16 + lg*4];
    #pragma unroll
    for (int bt = 0; bt < 4; bt++) {
      float v0 = fmaxf(acc[nt][bt][0] + bv.x, 0.f);
      float v1 = fmaxf(acc[nt][bt][1] + bv.y, 0.f);
      float v2 = fmaxf(acc[nt][bt][2] + bv.z, 0.f);
      float v3 = fmaxf(acc[nt][bt][3] + bv.w, 0.f);
      int m   = 16*bt + lr;
      int byt = (32*ct + 8*lg) ^ ((m & 7) << 4);
      uint2 pkd; pkd.x = pk2(v0, v1); pkd.y = pk2(v2, v3);
      *(uint2*)((char*)sH + m*512 + byt) = pkd;
    }
  }
  __syncthreads();

  // ========== G3^T: out^T = W3^T @ h2^T (n3 padded to 16), wave w: bt=w =====
  f32x4 acc3 = (f32x4){0.f,0.f,0.f,0.f};
  #pragma unroll
  for (int ks = 0; ks < 8; ks++) {
    int m = 16*wid + lr;
    int byt = (64*ks + 16*lg) ^ ((m & 7) << 4);
    s16x8 bb = *(const s16x8*)((const char*)sH + m*512 + byt);
    s16x8 a  = *(const s16x8*)(P + W3P_OFF + ((e*8 + ks) << 9) + lane*8);
    acc3 = __builtin_amdgcn_mfma_f32_16x16x32_bf16(a, bb, acc3, 0,0,0);
  }

  // lane (lg=0, lr): rows n3=0..3 of point m=16*wid+lr
  if (lg == 0) {
    int slot = t*64 + 16*wid + lr;
    float wv = (slot < cnt) ? wlist[e*NPTS + slot] : 0.f;
    if (wv != 0.f) {
      int p = (int)lists[e*NPTS + slot];
      #pragma unroll
      for (int r = 0; r < 4; r++)
        atomicAdd(&out[(size_t)p*DOUT + r], wv * (acc3[r] + b3[e*DOUT + r]));
    }
  }
}

// ---------------- launcher --------------------------------------------------
extern "C" void kernel_launch(void* const* d_in, const int* in_sizes, int n_in,
                              void* d_out, int out_size, void* d_ws, size_t ws_size,
                              hipStream_t stream) {
  const float* x   = (const float*)d_in[0];
  const float* cen = (const float*)d_in[1];
  const float* W1  = (const float*)d_in[2];
  const float* b1  = (const float*)d_in[3];
  const float* W2  = (const float*)d_in[4];
  const float* b2  = (const float*)d_in[5];
  const float* W3  = (const float*)d_in[6];
  const float* b3  = (const float*)d_in[7];

  unsigned short* P     = (unsigned short*)d_ws;
  int*            cnts  = (int*)((char*)d_ws + CNT_OFF);
  unsigned short* lists = (unsigned short*)((char*)d_ws + LIST_OFF);
  unsigned short* XB    = (unsigned short*)((char*)d_ws + XB_OFF);
  float*          WL    = (float*)((char*)d_ws + WL_OFF);
  float* out = (float*)d_out;

  (void)hipMemsetAsync(cnts, 0, 32, stream);
  fused_prep<<<dim3(PREP_BLKS + XPK_BLKS + RC_BLKS), dim3(256), 0, stream>>>(
      x, cen, W1, W2, W3, P, (unsigned*)XB, out, cnts, lists, WL);
  expert_mlp<<<dim3(NPTS/64, E_), dim3(256), 0, stream>>>(b1, b2, b3, P, XB,
                                                          cnts, lists, WL, out);
}